// Round 7
// baseline (484.021 us; speedup 1.0000x reference)
//
#include <hip/hip_runtime.h>
#include <math.h>

#define NND 50000
#define NED 800000
#define ETOT 850000   // edges + self-loops
#define NG 256
#define FEAT 128
#define CCH 256       // HEADS*HID
#define OUTD 128
#define NEG 0.2f
#define NBLK 196      // ceil(NND/256)
#define M2 50048      // NND padded to 128
#define XBLK 6250     // ceil(NND*FEAT/4 / 256)
#define SCATBLK 3321  // ceil(ETOT/256)
#define GEMMBLK (M2 / 64)   // 782

typedef __attribute__((ext_vector_type(8))) _Float16 half8;
typedef __attribute__((ext_vector_type(4))) _Float16 half4;
typedef __attribute__((ext_vector_type(4))) float floatx4;

#if __has_builtin(__builtin_amdgcn_global_load_lds)
#define GLOAD16(g, l) __builtin_amdgcn_global_load_lds( \
    (const __attribute__((address_space(1))) void*)(g), \
    (__attribute__((address_space(3))) void*)(l), 16, 0, 0)
#define HAVE_GLDS 1
#else
#define HAVE_GLDS 0
#endif

// ---------------- CSR build (scan stages; count lives in prep, scatter in gemm0) ----------------

__global__ __launch_bounds__(256) void scan_part_kernel(const int* __restrict__ deg,
                                                        int* __restrict__ bsum) {
    __shared__ int tile[256];
    int i = blockIdx.x * 256 + threadIdx.x;
    tile[threadIdx.x] = (i < NND) ? deg[i] : 0;
    __syncthreads();
    for (int s = 128; s > 0; s >>= 1) {
        if (threadIdx.x < s) tile[threadIdx.x] += tile[threadIdx.x + s];
        __syncthreads();
    }
    if (threadIdx.x == 0) bsum[blockIdx.x] = tile[0];
}

// merged: every block redundantly scans the 196 block sums in LDS (cheap),
// then does its local scan — removes the separate single-block scan_bsum
// dispatch and the boff/total round-trip (coop grid.sync measured 25-100us
// per sync on gfx950 — R15/R16 — so fusion must be sync-free).
__global__ __launch_bounds__(256) void scan_write_kernel(const int* __restrict__ deg,
                                                         const int* __restrict__ bsum,
                                                         int* __restrict__ rowptr,
                                                         int* __restrict__ cursor) {
    __shared__ int bs[256];
    __shared__ int tile[256];
    const int t = threadIdx.x, b = blockIdx.x;
    // inclusive scan of bsum (all blocks do this redundantly)
    bs[t] = (t < NBLK) ? bsum[t] : 0;
    __syncthreads();
    for (int off = 1; off < 256; off <<= 1) {
        int u = (t >= off) ? bs[t - off] : 0;
        __syncthreads();
        bs[t] += u;
        __syncthreads();
    }
    int boffb = (b == 0) ? 0 : bs[b - 1];
    int total = bs[NBLK - 1];
    // local scan of this block's 256 degrees
    int i = b * 256 + t;
    int v = (i < NND) ? deg[i] : 0;
    tile[t] = v;
    __syncthreads();
    for (int off = 1; off < 256; off <<= 1) {
        int u = (t >= off) ? tile[t - off] : 0;
        __syncthreads();
        tile[t] += u;
        __syncthreads();
    }
    if (i < NND) {
        int r = boffb + tile[t] - v;
        rowptr[i] = r;
        cursor[i] = r;
    }
    if (i == 0) rowptr[NND] = total;
}

// ---------------- fused prep: graph bounds | x->fp16 | W->fp16^T | COUNT ----------------
// R22: deg zeroing moved to hipMemsetAsync (before this dispatch); count's
// 850K atomicAdds fused in as trailing blocks so they overlap the 38MB
// x-conversion instead of running as a serial latency-bound dispatch.

__global__ __launch_bounds__(256) void prep_kernel(const int* __restrict__ batch,
                                                   int* __restrict__ deg,
                                                   int* __restrict__ gstart,
                                                   const float4* __restrict__ x,
                                                   half4* __restrict__ xo,
                                                   const float* __restrict__ W0,
                                                   const float* __restrict__ W1,
                                                   const float* __restrict__ W2,
                                                   _Float16* __restrict__ wt0,
                                                   _Float16* __restrict__ wt1,
                                                   _Float16* __restrict__ wt2,
                                                   const int* __restrict__ ei) {
    int b = blockIdx.x;
    if (b < 196) {
        int i = b * 256 + threadIdx.x;
        if (i >= NND) return;
        int bb = batch[i];
        int bp = (i == 0) ? -1 : batch[i - 1];
        for (int g = bp + 1; g <= bb; ++g) gstart[g] = i;
        if (i == NND - 1)
            for (int g = bb + 1; g <= NG; ++g) gstart[g] = NND;
        return;
    }
    b -= 196;
    if (b < XBLK) {
        int i = b * 256 + threadIdx.x;
        if (i >= NND * FEAT / 4) return;
        float4 v = x[i];
        half4 o;
        o[0] = (_Float16)v.x; o[1] = (_Float16)v.y;
        o[2] = (_Float16)v.z; o[3] = (_Float16)v.w;
        xo[i] = o;
        return;
    }
    b -= XBLK;
    int j = b * 256 + threadIdx.x;
    if (j < 256 * 128) {
        int n = j >> 7, k = j & 127;
        wt0[j] = (_Float16)W0[k * 256 + n];
        return;
    }
    j -= 256 * 128;
    if (j < 256 * 256) {
        int n = j >> 8, k = j & 255;
        wt1[j] = (_Float16)W1[k * 256 + n];
        return;
    }
    j -= 256 * 256;
    if (j < 256 * 256) {
        int n = j >> 8, k = j & 255;
        wt2[j] = (_Float16)W2[k * 256 + n];
        return;
    }
    j -= 256 * 256;
    // count section (deg zeroed by the preceding hipMemsetAsync)
    if (j < ETOT) {
        int dst = (j < NED) ? ei[NED + j] : (j - NED);
        atomicAdd(&deg[dst], 1);
    }
}

// ---------------- MFMA GEMM + fused alpha epilogue (+ scatter on layer 0) ----------------
// R21 structure: BM=64, BN=256 (full N) per block; A staged once, B L2-resident.
// R22: layer 0 launches with SCATBLK extra blocks that run the CSR scatter
// (850K cursor atomics + random 4B writes) concurrently with the MFMA blocks —
// hides the scatter's latency-bound thrash under gemm instead of a serial
// dispatch. Guarded early, no __syncthreads on that path.

#define BK 64

__global__ __launch_bounds__(256, 3) void gemm_mfma_kernel(
        const _Float16* __restrict__ A,
        const _Float16* __restrict__ Bt,
        const float* __restrict__ as_, const float* __restrict__ ad_,
        _Float16* __restrict__ Hm,
        float* __restrict__ asrc, float* __restrict__ adst, int K,
        int gemmBlocks,
        const int* __restrict__ ei, int* __restrict__ cursor,
        int* __restrict__ csrsrc) {
    if ((int)blockIdx.x >= gemmBlocks) {
        // scatter path
        int e = ((int)blockIdx.x - gemmBlocks) * 256 + threadIdx.x;
        if (e < ETOT) {
            int s, d;
            if (e < NED) { s = ei[e]; d = ei[NED + e]; } else { s = d = e - NED; }
            int pos = atomicAdd(&cursor[d], 1);
            csrsrc[pos] = s;
        }
        return;
    }
    __shared__ _Float16 AsF[64 * 64];    // 8KB
    __shared__ _Float16 BsF[256 * 64];   // 32KB
    const int t = threadIdx.x;
    const int bm = blockIdx.x * 64;
    const int lane = t & 63, wv = t >> 6;
    const int wn = wv * 64;
    const int fr = lane & 15, q = lane >> 4;

    floatx4 acc[4][4] = {};

    const int lrow = t >> 3;          // 0..31
    const int c8 = t & 7;             // 16B block slot within LDS row

    for (int k0 = 0; k0 < K; k0 += BK) {
        // stage A: 64 rows in 2 passes
        for (int p = 0; p < 2; p++) {
            int row = p * 32 + lrow;
            int g8 = c8 ^ (row & 7);  // swizzled global block
            const _Float16* ga = A + (size_t)(bm + row) * K + k0 + g8 * 8;
#if HAVE_GLDS
            GLOAD16(ga, &AsF[row * 64 + c8 * 8]);
#else
            *(half8*)&AsF[row * 64 + c8 * 8] = *(const half8*)ga;
#endif
        }
        // stage B: 256 rows in 8 passes
        for (int p = 0; p < 8; p++) {
            int row = p * 32 + lrow;
            int g8 = c8 ^ (row & 7);
            const _Float16* gb = Bt + (size_t)row * K + k0 + g8 * 8;
#if HAVE_GLDS
            GLOAD16(gb, &BsF[row * 64 + c8 * 8]);
#else
            *(half8*)&BsF[row * 64 + c8 * 8] = *(const half8*)gb;
#endif
        }
        __syncthreads();
        for (int kc = 0; kc < 2; kc++) {
            half8 af[4], bf[4];
            int kb = kc * 4 + q;      // 16B k-block of this quad's fragment
            int cs = (kb ^ (fr & 7)) * 8;
            for (int mi = 0; mi < 4; mi++)
                af[mi] = *(const half8*)&AsF[(mi * 16 + fr) * 64 + cs];
            for (int ni = 0; ni < 4; ni++)
                bf[ni] = *(const half8*)&BsF[(wn + ni * 16 + fr) * 64 + cs];
            for (int mi = 0; mi < 4; mi++)
                for (int ni = 0; ni < 4; ni++)
                    acc[mi][ni] = __builtin_amdgcn_mfma_f32_16x16x32_f16(
                        af[mi], bf[ni], acc[mi][ni], 0, 0, 0);
        }
        __syncthreads();
    }

    // C/D layout: col = lane&15 (fr), row = q*4 + reg
    for (int mi = 0; mi < 4; mi++) {
        int row0 = bm + mi * 16 + q * 4;
        for (int ni = 0; ni < 4; ni++) {
            int col = wn + ni * 16 + fr;
            for (int r = 0; r < 4; r++)
                Hm[(size_t)(row0 + r) * CCH + col] = (_Float16)acc[mi][ni][r];
        }
    }

    // fused alpha: this wave's head (wn>>6 == wv)
    const int hd = wv;
    float asf[4], adf[4];
    for (int ni = 0; ni < 4; ni++) {
        asf[ni] = as_[hd * 64 + ni * 16 + fr];
        adf[ni] = ad_[hd * 64 + ni * 16 + fr];
    }
    for (int mi = 0; mi < 4; mi++)
        for (int r = 0; r < 4; r++) {
            float ps = 0.f, pd = 0.f;
            for (int ni = 0; ni < 4; ni++) {
                float v = acc[mi][ni][r];
                ps += v * asf[ni];
                pd += v * adf[ni];
            }
            for (int m = 1; m < 16; m <<= 1) {
                ps += __shfl_xor(ps, m, 64);
                pd += __shfl_xor(pd, m, 64);
            }
            if (fr == 0) {
                int row = bm + mi * 16 + q * 4 + r;
                asrc[row * 4 + hd] = ps;
                adst[row * 4 + hd] = pd;
            }
        }
}

// ---------------- fused softmax + weighted fp16 gather + bias + ELU -> fp16 ----------------
// One wave per dst node (R17 structure — final: the (node,head) 4-way split
// (R18) and (node,half) 2-way split (R20) both cut FETCH via XCD pinning but
// regressed duration; agg sits at a joint issue + random-128B-line equilibrium
// at ~70us, FETCH = the 8-XCD unique-row floor of 208MB).

__global__ __launch_bounds__(256) void agg_kernel(const _Float16* __restrict__ H16,
                                                  const float* __restrict__ asrc,
                                                  const float* __restrict__ adst,
                                                  const int* __restrict__ rowptr,
                                                  const int* __restrict__ csrsrc,
                                                  const float4* __restrict__ bias4,
                                                  half8* __restrict__ xo) {
    int wave = threadIdx.x >> 6, lane = threadIdx.x & 63;
    int n = blockIdx.x * 4 + wave;
    if (n >= NND) return;
    int rs = rowptr[n], re = rowptr[n + 1];
    int hd = lane >> 4;          // head for exp computation
    int sub = lane & 15;
    int l32 = lane & 31;         // output channel-group (8 ch)
    int myh = l32 >> 3;          // head of my output channels
    int epar = lane >> 5;        // edge parity this half handles
    float adv = adst[n * 4 + hd];
    float acc[8] = {};
    float ssum = 0.f;
    const char* hbyte = (const char*)H16;   // uniform base -> SADDR loads
    unsigned loff = (unsigned)l32 * 16u;    // per-lane channel byte offset

    // prologue prefetch (edge slot = sub)
    int sl = rs + sub;
    bool ok = sl < re;
    int idx = ok ? csrsrc[sl] : 0;
    unsigned off = (unsigned)idx << 9;      // row byte offset (idx*CCH*2)
    float aval = asrc[idx * 4 + hd];

    int e0 = rs;
    // ---- full 16-edge chunks: branch-free, deep-pipelined ----
    while (re - e0 >= 16) {
        float a = aval + adv;
        a = fmaxf(a, NEG * a);              // leaky relu (NEG>0)
        float ev = __expf(a);
        ssum += ev;
        unsigned offcur = off;
        // prefetch next chunk (may be the tail)
        int sl2 = e0 + 16 + sub;
        bool ok2 = sl2 < re;
        int idx2 = ok2 ? csrsrc[sl2] : 0;
        off = (unsigned)idx2 << 9;
        aval = asrc[idx2 * 4 + hd];
        ok = ok2;

        half8 hv[8];
        float wws[8];
        #pragma unroll
        for (int j2 = 0; j2 < 8; j2++) {
            int j = j2 * 2 + epar;
            unsigned o = __shfl(offcur, j, 64);
            wws[j2] = __shfl(ev, myh * 16 + j, 64);
            hv[j2] = *(const half8*)(hbyte + (o + loff));
        }
        #pragma unroll
        for (int j2 = 0; j2 < 8; j2++) {
            float ww = wws[j2];
            #pragma unroll
            for (int k = 0; k < 8; k++)
                acc[k] += ww * (float)hv[j2][k];
        }
        e0 += 16;
    }
    // ---- tail chunk (<16 edges) ----
    if (e0 < re) {
        float a = aval + adv;
        a = fmaxf(a, NEG * a);
        float ev = ok ? __expf(a) : 0.f;
        ssum += ev;
        int cnt = re - e0;
        #pragma unroll
        for (int j2 = 0; j2 < 8; j2++) {
            if (j2 * 2 >= cnt) break;
            int j = j2 * 2 + epar;
            unsigned o = __shfl(off, j, 64);
            float ww = __shfl(ev, myh * 16 + j, 64);
            half8 hv = *(const half8*)(hbyte + (o + loff));
            #pragma unroll
            for (int k = 0; k < 8; k++)
                acc[k] += ww * (float)hv[k];
        }
    }
    // per-head softmax denominator: reduce over the 16 sub-lanes of each quarter
    for (int sft = 1; sft < 16; sft <<= 1) ssum += __shfl_xor(ssum, sft, 64);
    float inv = 1.f / __shfl(ssum, myh * 16, 64);
    // fold the two edge-parity halves
    #pragma unroll
    for (int k = 0; k < 8; k++) acc[k] += __shfl_xor(acc[k], 32, 64);
    if (lane < 32) {
        float4 b0 = bias4[l32 * 2], b1 = bias4[l32 * 2 + 1];
        float o[8];
        o[0] = acc[0] * inv + b0.x; o[1] = acc[1] * inv + b0.y;
        o[2] = acc[2] * inv + b0.z; o[3] = acc[3] * inv + b0.w;
        o[4] = acc[4] * inv + b1.x; o[5] = acc[5] * inv + b1.y;
        o[6] = acc[6] * inv + b1.z; o[7] = acc[7] * inv + b1.w;
        half8 h;
        #pragma unroll
        for (int k = 0; k < 8; k++) {
            float v = o[k];
            v = v > 0.f ? v : expm1f(v);
            h[k] = (_Float16)v;
        }
        xo[(size_t)n * 32 + l32] = h;
    }
}

// ---------------- pooling + final linear + L2 norm (fused) ----------------
// R19: 1024 threads/block. Mean phase: 4-way node-parallel (qt = t>>8) with
// coalesced 128B wave loads. Matmul phase: 8 K-slices x 128 outputs with LDS
// reduce.

__global__ __launch_bounds__(1024) void poolfinal_kernel(const _Float16* __restrict__ xa,
                                                         const int* __restrict__ gstart,
                                                         const float* __restrict__ Wf,
                                                         const float* __restrict__ bfv,
                                                         float* __restrict__ out) {
    int g = blockIdx.x, t = threadIdx.x;
    int ch = t & 255, qt = t >> 8;       // channel, node-quarter
    __shared__ float part[4][256];
    __shared__ float gm[256];
    __shared__ float mm[8][128];
    __shared__ float red[128];
    int s = gstart[g], e = gstart[g + 1];
    int cnt = e - s;
    float acc = 0.f;
    for (int i = s + qt; i < e; i += 4)
        acc += (float)xa[(size_t)i * CCH + ch];
    part[qt][ch] = acc;
    __syncthreads();
    if (qt == 0)
        gm[ch] = (part[0][ch] + part[1][ch] + part[2][ch] + part[3][ch])
                 / (float)(cnt > 0 ? cnt : 1);
    __syncthreads();
    // matmul: 1024 threads = 128 outputs x 8 K-slices of 32
    int j = t & 127, ks = t >> 7;
    float a = 0.f;
    for (int k = ks * 32; k < ks * 32 + 32; k++)
        a += gm[k] * Wf[k * OUTD + j];
    mm[ks][j] = a;
    __syncthreads();
    if (t < OUTD) {
        float v = bfv[j];
        for (int q = 0; q < 8; q++) v += mm[q][j];
        red[j] = v * v;
        mm[0][j] = v;          // stash numerator
    }
    __syncthreads();
    for (int sft = 64; sft > 0; sft >>= 1) {
        if (t < sft) red[t] += red[t + sft];
        __syncthreads();
    }
    if (t < OUTD) out[g * OUTD + t] = mm[0][t] / fmaxf(sqrtf(red[0]), 1e-12f);
}

// ---------------- launch ----------------

extern "C" void kernel_launch(void* const* d_in, const int* in_sizes, int n_in,
                              void* d_out, int out_size, void* d_ws, size_t ws_size,
                              hipStream_t stream) {
    const float* x     = (const float*)d_in[0];
    const int*   ei    = (const int*)d_in[1];
    const int*   batch = (const int*)d_in[2];
    const float* W[3]  = {(const float*)d_in[3], (const float*)d_in[7],  (const float*)d_in[11]};
    const float* As[3] = {(const float*)d_in[4], (const float*)d_in[8],  (const float*)d_in[12]};
    const float* Ad[3] = {(const float*)d_in[5], (const float*)d_in[9],  (const float*)d_in[13]};
    const float* Bb[3] = {(const float*)d_in[6], (const float*)d_in[10], (const float*)d_in[14]};
    const float* Wf    = (const float*)d_in[15];
    const float* bf    = (const float*)d_in[16];
    float* out = (float*)d_out;

    // workspace layout
    _Float16* H16   = (_Float16*)d_ws;                            // M2*256 fp16 (gemm out / gather in)
    _Float16* act16 = H16 + (size_t)M2 * CCH;                     // M2*256 fp16 (agg out / gemm in)
    _Float16* wt0   = act16 + (size_t)M2 * CCH;                   // 256*128
    _Float16* wt1   = wt0 + 256 * 128;                            // 256*256
    _Float16* wt2   = wt1 + 256 * 256;                            // 256*256
    float* asrc  = (float*)(wt2 + 256 * 256);                     // M2*4
    float* adst  = asrc + (size_t)M2 * 4;                         // M2*4
    int* deg     = (int*)(adst + (size_t)M2 * 4);                 // NND+1
    int* rowptr  = deg + (NND + 1);
    int* cursor  = rowptr + (NND + 1);
    int* csrsrc  = cursor + (NND + 1);                            // ETOT
    int* gstart  = csrsrc + ETOT;                                 // NG+1
    int* bsum    = gstart + (NG + 1);                             // NBLK

    _Float16* wt[3] = {wt0, wt1, wt2};

    // zero deg asynchronously (replaces prep's zero section)
    hipMemsetAsync(deg, 0, (NND + 1) * sizeof(int), stream);

    // fused prep (bounds | x->fp16 | W->fp16^T | count atomics)
    prep_kernel<<<196 + XBLK + 640 + SCATBLK, 256, 0, stream>>>(
        batch, deg, gstart, (const float4*)x, (half4*)act16,
        W[0], W[1], W[2], wt0, wt1, wt2, ei);
    scan_part_kernel<<<NBLK, 256, 0, stream>>>(deg, bsum);
    scan_write_kernel<<<NBLK, 256, 0, stream>>>(deg, bsum, rowptr, cursor);

    // 3 GAT layers; layer 0's gemm carries the CSR scatter as extra blocks
    int K = FEAT;
    for (int l = 0; l < 3; l++) {
        int grid = (l == 0) ? (GEMMBLK + SCATBLK) : GEMMBLK;
        gemm_mfma_kernel<<<grid, 256, 0, stream>>>(act16, wt[l], As[l], Ad[l], H16,
                                                   asrc, adst, K, GEMMBLK,
                                                   ei, cursor, csrsrc);
        agg_kernel<<<(NND + 3) / 4, 256, 0, stream>>>(H16, asrc, adst, rowptr, csrsrc,
                                                      (const float4*)Bb[l], (half8*)act16);
        K = CCH;
    }

    // global mean pool + final linear + L2 normalize (fused)
    poolfinal_kernel<<<NG, 1024, 0, stream>>>(act16, gstart, Wf, bf, out);
}

// Round 8
// 473.739 us; speedup vs baseline: 1.0217x; 1.0217x over previous
//
#include <hip/hip_runtime.h>
#include <math.h>

#define NND 50000
#define NED 800000
#define ETOT 850000   // edges + self-loops
#define NG 256
#define FEAT 128
#define CCH 256       // HEADS*HID
#define OUTD 128
#define NEG 0.2f
#define NBLK 196      // ceil(NND/256)
#define M2 50048      // NND padded to 128
#define XBLK 6250     // ceil(NND*FEAT/4 / 256)
#define SCATBLK 3321  // ceil(ETOT/256)
#define GEMMBLK (M2 / 64)   // 782

typedef __attribute__((ext_vector_type(8))) _Float16 half8;
typedef __attribute__((ext_vector_type(4))) _Float16 half4;
typedef __attribute__((ext_vector_type(4))) float floatx4;

#if __has_builtin(__builtin_amdgcn_global_load_lds)
#define GLOAD16(g, l) __builtin_amdgcn_global_load_lds( \
    (const __attribute__((address_space(1))) void*)(g), \
    (__attribute__((address_space(3))) void*)(l), 16, 0, 0)
#define HAVE_GLDS 1
#else
#define HAVE_GLDS 0
#endif

// ---------------- CSR build (scan stages; count lives in prep, scatter in gemm0) ----------------

__global__ __launch_bounds__(256) void scan_part_kernel(const int* __restrict__ deg,
                                                        int* __restrict__ bsum) {
    __shared__ int tile[256];
    int i = blockIdx.x * 256 + threadIdx.x;
    tile[threadIdx.x] = (i < NND) ? deg[i] : 0;
    __syncthreads();
    for (int s = 128; s > 0; s >>= 1) {
        if (threadIdx.x < s) tile[threadIdx.x] += tile[threadIdx.x + s];
        __syncthreads();
    }
    if (threadIdx.x == 0) bsum[blockIdx.x] = tile[0];
}

// merged: every block redundantly scans the 196 block sums in LDS (cheap),
// then does its local scan — removes the separate single-block scan_bsum
// dispatch and the boff/total round-trip (coop grid.sync measured 25-100us
// per sync on gfx950 — R15/R16 — so fusion must be sync-free).
__global__ __launch_bounds__(256) void scan_write_kernel(const int* __restrict__ deg,
                                                         const int* __restrict__ bsum,
                                                         int* __restrict__ rowptr,
                                                         int* __restrict__ cursor) {
    __shared__ int bs[256];
    __shared__ int tile[256];
    const int t = threadIdx.x, b = blockIdx.x;
    // inclusive scan of bsum (all blocks do this redundantly)
    bs[t] = (t < NBLK) ? bsum[t] : 0;
    __syncthreads();
    for (int off = 1; off < 256; off <<= 1) {
        int u = (t >= off) ? bs[t - off] : 0;
        __syncthreads();
        bs[t] += u;
        __syncthreads();
    }
    int boffb = (b == 0) ? 0 : bs[b - 1];
    int total = bs[NBLK - 1];
    // local scan of this block's 256 degrees
    int i = b * 256 + t;
    int v = (i < NND) ? deg[i] : 0;
    tile[t] = v;
    __syncthreads();
    for (int off = 1; off < 256; off <<= 1) {
        int u = (t >= off) ? tile[t - off] : 0;
        __syncthreads();
        tile[t] += u;
        __syncthreads();
    }
    if (i < NND) {
        int r = boffb + tile[t] - v;
        rowptr[i] = r;
        cursor[i] = r;
    }
    if (i == 0) rowptr[NND] = total;
}

// ---------------- fused prep: graph bounds | x->fp16 | W->fp16^T | COUNT ----------------
// R22: deg zeroing via hipMemsetAsync; count's 850K atomicAdds fused in as
// trailing blocks so they overlap the 38MB x-conversion.

__global__ __launch_bounds__(256) void prep_kernel(const int* __restrict__ batch,
                                                   int* __restrict__ deg,
                                                   int* __restrict__ gstart,
                                                   const float4* __restrict__ x,
                                                   half4* __restrict__ xo,
                                                   const float* __restrict__ W0,
                                                   const float* __restrict__ W1,
                                                   const float* __restrict__ W2,
                                                   _Float16* __restrict__ wt0,
                                                   _Float16* __restrict__ wt1,
                                                   _Float16* __restrict__ wt2,
                                                   const int* __restrict__ ei) {
    int b = blockIdx.x;
    if (b < 196) {
        int i = b * 256 + threadIdx.x;
        if (i >= NND) return;
        int bb = batch[i];
        int bp = (i == 0) ? -1 : batch[i - 1];
        for (int g = bp + 1; g <= bb; ++g) gstart[g] = i;
        if (i == NND - 1)
            for (int g = bb + 1; g <= NG; ++g) gstart[g] = NND;
        return;
    }
    b -= 196;
    if (b < XBLK) {
        int i = b * 256 + threadIdx.x;
        if (i >= NND * FEAT / 4) return;
        float4 v = x[i];
        half4 o;
        o[0] = (_Float16)v.x; o[1] = (_Float16)v.y;
        o[2] = (_Float16)v.z; o[3] = (_Float16)v.w;
        xo[i] = o;
        return;
    }
    b -= XBLK;
    int j = b * 256 + threadIdx.x;
    if (j < 256 * 128) {
        int n = j >> 7, k = j & 127;
        wt0[j] = (_Float16)W0[k * 256 + n];
        return;
    }
    j -= 256 * 128;
    if (j < 256 * 256) {
        int n = j >> 8, k = j & 255;
        wt1[j] = (_Float16)W1[k * 256 + n];
        return;
    }
    j -= 256 * 256;
    if (j < 256 * 256) {
        int n = j >> 8, k = j & 255;
        wt2[j] = (_Float16)W2[k * 256 + n];
        return;
    }
    j -= 256 * 256;
    // count section (deg zeroed by the preceding hipMemsetAsync)
    if (j < ETOT) {
        int dst = (j < NED) ? ei[NED + j] : (j - NED);
        atomicAdd(&deg[dst], 1);
    }
}

// ---------------- MFMA GEMM + fused alpha epilogue (+ scatter on layer 0) ----------------
// R21 structure: BM=64, BN=256 (full N); A staged once, B L2-resident.
// R23: store-path fix. The old epilogue issued 64 scalar 2B C-stores + 32
// scattered 4B alpha-stores per thread -> WRITE_SIZE 81.6MB (3x ideal), gemm
// 72us with all pipes <5% (store-drain bound). Now: restage C into BsF (dead
// after the K-loop) and alpha partials into AsF, one barrier, then 8x 16B
// contiguous half8 stores + 2 coalesced 4B stores per thread.

#define BK 64

__global__ __launch_bounds__(256, 3) void gemm_mfma_kernel(
        const _Float16* __restrict__ A,
        const _Float16* __restrict__ Bt,
        const float* __restrict__ as_, const float* __restrict__ ad_,
        _Float16* __restrict__ Hm,
        float* __restrict__ asrc, float* __restrict__ adst, int K,
        int gemmBlocks,
        const int* __restrict__ ei, int* __restrict__ cursor,
        int* __restrict__ csrsrc) {
    if ((int)blockIdx.x >= gemmBlocks) {
        // scatter path
        int e = ((int)blockIdx.x - gemmBlocks) * 256 + threadIdx.x;
        if (e < ETOT) {
            int s, d;
            if (e < NED) { s = ei[e]; d = ei[NED + e]; } else { s = d = e - NED; }
            int pos = atomicAdd(&cursor[d], 1);
            csrsrc[pos] = s;
        }
        return;
    }
    __shared__ _Float16 AsF[64 * 64];    // 8KB  (K-loop A tile; epilogue alpha buf)
    __shared__ _Float16 BsF[256 * 64];   // 32KB (K-loop B tile; epilogue C tile)
    const int t = threadIdx.x;
    const int bm = blockIdx.x * 64;
    const int lane = t & 63, wv = t >> 6;
    const int wn = wv * 64;
    const int fr = lane & 15, q = lane >> 4;

    floatx4 acc[4][4] = {};

    const int lrow = t >> 3;          // 0..31
    const int c8 = t & 7;             // 16B block slot within LDS row

    for (int k0 = 0; k0 < K; k0 += BK) {
        // stage A: 64 rows in 2 passes
        for (int p = 0; p < 2; p++) {
            int row = p * 32 + lrow;
            int g8 = c8 ^ (row & 7);  // swizzled global block
            const _Float16* ga = A + (size_t)(bm + row) * K + k0 + g8 * 8;
#if HAVE_GLDS
            GLOAD16(ga, &AsF[row * 64 + c8 * 8]);
#else
            *(half8*)&AsF[row * 64 + c8 * 8] = *(const half8*)ga;
#endif
        }
        // stage B: 256 rows in 8 passes
        for (int p = 0; p < 8; p++) {
            int row = p * 32 + lrow;
            int g8 = c8 ^ (row & 7);
            const _Float16* gb = Bt + (size_t)row * K + k0 + g8 * 8;
#if HAVE_GLDS
            GLOAD16(gb, &BsF[row * 64 + c8 * 8]);
#else
            *(half8*)&BsF[row * 64 + c8 * 8] = *(const half8*)gb;
#endif
        }
        __syncthreads();
        for (int kc = 0; kc < 2; kc++) {
            half8 af[4], bf[4];
            int kb = kc * 4 + q;      // 16B k-block of this quad's fragment
            int cs = (kb ^ (fr & 7)) * 8;
            for (int mi = 0; mi < 4; mi++)
                af[mi] = *(const half8*)&AsF[(mi * 16 + fr) * 64 + cs];
            for (int ni = 0; ni < 4; ni++)
                bf[ni] = *(const half8*)&BsF[(wn + ni * 16 + fr) * 64 + cs];
            for (int mi = 0; mi < 4; mi++)
                for (int ni = 0; ni < 4; ni++)
                    acc[mi][ni] = __builtin_amdgcn_mfma_f32_16x16x32_f16(
                        af[mi], bf[ni], acc[mi][ni], 0, 0, 0);
        }
        __syncthreads();
    }

    // ---- epilogue: restage through LDS, then coalesced writeout ----
    // C/D layout: col = lane&15 (fr), row = q*4 + reg
    _Float16* Cs = BsF;                 // [64][256] C tile (BsF dead)
    for (int mi = 0; mi < 4; mi++)
        for (int ni = 0; ni < 4; ni++)
            for (int r = 0; r < 4; r++)
                Cs[(mi * 16 + q * 4 + r) * 256 + wn + ni * 16 + fr] =
                    (_Float16)acc[mi][ni][r];

    // fused alpha: this wave's head (wn>>6 == wv)
    float* Pfs = (float*)AsF;           // [64][4] ps
    float* Pfd = Pfs + 256;             // [64][4] pd
    const int hd = wv;
    float asf[4], adf[4];
    for (int ni = 0; ni < 4; ni++) {
        asf[ni] = as_[hd * 64 + ni * 16 + fr];
        adf[ni] = ad_[hd * 64 + ni * 16 + fr];
    }
    for (int mi = 0; mi < 4; mi++)
        for (int r = 0; r < 4; r++) {
            float ps = 0.f, pd = 0.f;
            for (int ni = 0; ni < 4; ni++) {
                float v = acc[mi][ni][r];
                ps += v * asf[ni];
                pd += v * adf[ni];
            }
            for (int m = 1; m < 16; m <<= 1) {
                ps += __shfl_xor(ps, m, 64);
                pd += __shfl_xor(pd, m, 64);
            }
            if (fr == 0) {
                int row = mi * 16 + q * 4 + r;   // local row
                Pfs[row * 4 + hd] = ps;
                Pfd[row * 4 + hd] = pd;
            }
        }
    __syncthreads();

    // coalesced stores: 8 x half8 (16B) per thread, contiguous per wave
    half8* Hv = (half8*)(Hm + (size_t)bm * CCH);
    const half8* Cv = (const half8*)Cs;
    #pragma unroll
    for (int p = 0; p < 8; p++)
        Hv[p * 256 + t] = Cv[p * 256 + t];
    asrc[bm * 4 + t] = Pfs[t];
    adst[bm * 4 + t] = Pfd[t];
}

// ---------------- fused softmax + weighted fp16 gather + bias + ELU -> fp16 ----------------
// One wave per dst node (R17 structure — final: the (node,head) 4-way split
// (R18) and (node,half) 2-way split (R20) both cut FETCH via XCD pinning but
// regressed duration; agg sits at a joint issue + random-128B-line equilibrium
// at ~70us, FETCH = the 8-XCD unique-row floor of 208MB).

__global__ __launch_bounds__(256) void agg_kernel(const _Float16* __restrict__ H16,
                                                  const float* __restrict__ asrc,
                                                  const float* __restrict__ adst,
                                                  const int* __restrict__ rowptr,
                                                  const int* __restrict__ csrsrc,
                                                  const float4* __restrict__ bias4,
                                                  half8* __restrict__ xo) {
    int wave = threadIdx.x >> 6, lane = threadIdx.x & 63;
    int n = blockIdx.x * 4 + wave;
    if (n >= NND) return;
    int rs = rowptr[n], re = rowptr[n + 1];
    int hd = lane >> 4;          // head for exp computation
    int sub = lane & 15;
    int l32 = lane & 31;         // output channel-group (8 ch)
    int myh = l32 >> 3;          // head of my output channels
    int epar = lane >> 5;        // edge parity this half handles
    float adv = adst[n * 4 + hd];
    float acc[8] = {};
    float ssum = 0.f;
    const char* hbyte = (const char*)H16;   // uniform base -> SADDR loads
    unsigned loff = (unsigned)l32 * 16u;    // per-lane channel byte offset

    // prologue prefetch (edge slot = sub)
    int sl = rs + sub;
    bool ok = sl < re;
    int idx = ok ? csrsrc[sl] : 0;
    unsigned off = (unsigned)idx << 9;      // row byte offset (idx*CCH*2)
    float aval = asrc[idx * 4 + hd];

    int e0 = rs;
    // ---- full 16-edge chunks: branch-free, deep-pipelined ----
    while (re - e0 >= 16) {
        float a = aval + adv;
        a = fmaxf(a, NEG * a);              // leaky relu (NEG>0)
        float ev = __expf(a);
        ssum += ev;
        unsigned offcur = off;
        // prefetch next chunk (may be the tail)
        int sl2 = e0 + 16 + sub;
        bool ok2 = sl2 < re;
        int idx2 = ok2 ? csrsrc[sl2] : 0;
        off = (unsigned)idx2 << 9;
        aval = asrc[idx2 * 4 + hd];
        ok = ok2;

        half8 hv[8];
        float wws[8];
        #pragma unroll
        for (int j2 = 0; j2 < 8; j2++) {
            int j = j2 * 2 + epar;
            unsigned o = __shfl(offcur, j, 64);
            wws[j2] = __shfl(ev, myh * 16 + j, 64);
            hv[j2] = *(const half8*)(hbyte + (o + loff));
        }
        #pragma unroll
        for (int j2 = 0; j2 < 8; j2++) {
            float ww = wws[j2];
            #pragma unroll
            for (int k = 0; k < 8; k++)
                acc[k] += ww * (float)hv[j2][k];
        }
        e0 += 16;
    }
    // ---- tail chunk (<16 edges) ----
    if (e0 < re) {
        float a = aval + adv;
        a = fmaxf(a, NEG * a);
        float ev = ok ? __expf(a) : 0.f;
        ssum += ev;
        int cnt = re - e0;
        #pragma unroll
        for (int j2 = 0; j2 < 8; j2++) {
            if (j2 * 2 >= cnt) break;
            int j = j2 * 2 + epar;
            unsigned o = __shfl(off, j, 64);
            float ww = __shfl(ev, myh * 16 + j, 64);
            half8 hv = *(const half8*)(hbyte + (o + loff));
            #pragma unroll
            for (int k = 0; k < 8; k++)
                acc[k] += ww * (float)hv[k];
        }
    }
    // per-head softmax denominator: reduce over the 16 sub-lanes of each quarter
    for (int sft = 1; sft < 16; sft <<= 1) ssum += __shfl_xor(ssum, sft, 64);
    float inv = 1.f / __shfl(ssum, myh * 16, 64);
    // fold the two edge-parity halves
    #pragma unroll
    for (int k = 0; k < 8; k++) acc[k] += __shfl_xor(acc[k], 32, 64);
    if (lane < 32) {
        float4 b0 = bias4[l32 * 2], b1 = bias4[l32 * 2 + 1];
        float o[8];
        o[0] = acc[0] * inv + b0.x; o[1] = acc[1] * inv + b0.y;
        o[2] = acc[2] * inv + b0.z; o[3] = acc[3] * inv + b0.w;
        o[4] = acc[4] * inv + b1.x; o[5] = acc[5] * inv + b1.y;
        o[6] = acc[6] * inv + b1.z; o[7] = acc[7] * inv + b1.w;
        half8 h;
        #pragma unroll
        for (int k = 0; k < 8; k++) {
            float v = o[k];
            v = v > 0.f ? v : expm1f(v);
            h[k] = (_Float16)v;
        }
        xo[(size_t)n * 32 + l32] = h;
    }
}

// ---------------- pooling + final linear + L2 norm (fused) ----------------
// R19: 1024 threads/block. Mean phase: 4-way node-parallel (qt = t>>8) with
// coalesced 128B wave loads. Matmul phase: 8 K-slices x 128 outputs with LDS
// reduce.

__global__ __launch_bounds__(1024) void poolfinal_kernel(const _Float16* __restrict__ xa,
                                                         const int* __restrict__ gstart,
                                                         const float* __restrict__ Wf,
                                                         const float* __restrict__ bfv,
                                                         float* __restrict__ out) {
    int g = blockIdx.x, t = threadIdx.x;
    int ch = t & 255, qt = t >> 8;       // channel, node-quarter
    __shared__ float part[4][256];
    __shared__ float gm[256];
    __shared__ float mm[8][128];
    __shared__ float red[128];
    int s = gstart[g], e = gstart[g + 1];
    int cnt = e - s;
    float acc = 0.f;
    for (int i = s + qt; i < e; i += 4)
        acc += (float)xa[(size_t)i * CCH + ch];
    part[qt][ch] = acc;
    __syncthreads();
    if (qt == 0)
        gm[ch] = (part[0][ch] + part[1][ch] + part[2][ch] + part[3][ch])
                 / (float)(cnt > 0 ? cnt : 1);
    __syncthreads();
    // matmul: 1024 threads = 128 outputs x 8 K-slices of 32
    int j = t & 127, ks = t >> 7;
    float a = 0.f;
    for (int k = ks * 32; k < ks * 32 + 32; k++)
        a += gm[k] * Wf[k * OUTD + j];
    mm[ks][j] = a;
    __syncthreads();
    if (t < OUTD) {
        float v = bfv[j];
        for (int q = 0; q < 8; q++) v += mm[q][j];
        red[j] = v * v;
        mm[0][j] = v;          // stash numerator
    }
    __syncthreads();
    for (int sft = 64; sft > 0; sft >>= 1) {
        if (t < sft) red[t] += red[t + sft];
        __syncthreads();
    }
    if (t < OUTD) out[g * OUTD + t] = mm[0][t] / fmaxf(sqrtf(red[0]), 1e-12f);
}

// ---------------- launch ----------------

extern "C" void kernel_launch(void* const* d_in, const int* in_sizes, int n_in,
                              void* d_out, int out_size, void* d_ws, size_t ws_size,
                              hipStream_t stream) {
    const float* x     = (const float*)d_in[0];
    const int*   ei    = (const int*)d_in[1];
    const int*   batch = (const int*)d_in[2];
    const float* W[3]  = {(const float*)d_in[3], (const float*)d_in[7],  (const float*)d_in[11]};
    const float* As[3] = {(const float*)d_in[4], (const float*)d_in[8],  (const float*)d_in[12]};
    const float* Ad[3] = {(const float*)d_in[5], (const float*)d_in[9],  (const float*)d_in[13]};
    const float* Bb[3] = {(const float*)d_in[6], (const float*)d_in[10], (const float*)d_in[14]};
    const float* Wf    = (const float*)d_in[15];
    const float* bf    = (const float*)d_in[16];
    float* out = (float*)d_out;

    // workspace layout
    _Float16* H16   = (_Float16*)d_ws;                            // M2*256 fp16 (gemm out / gather in)
    _Float16* act16 = H16 + (size_t)M2 * CCH;                     // M2*256 fp16 (agg out / gemm in)
    _Float16* wt0   = act16 + (size_t)M2 * CCH;                   // 256*128
    _Float16* wt1   = wt0 + 256 * 128;                            // 256*256
    _Float16* wt2   = wt1 + 256 * 256;                            // 256*256
    float* asrc  = (float*)(wt2 + 256 * 256);                     // M2*4
    float* adst  = asrc + (size_t)M2 * 4;                         // M2*4
    int* deg     = (int*)(adst + (size_t)M2 * 4);                 // NND+1
    int* rowptr  = deg + (NND + 1);
    int* cursor  = rowptr + (NND + 1);
    int* csrsrc  = cursor + (NND + 1);                            // ETOT
    int* gstart  = csrsrc + ETOT;                                 // NG+1
    int* bsum    = gstart + (NG + 1);                             // NBLK

    _Float16* wt[3] = {wt0, wt1, wt2};

    // zero deg asynchronously (replaces prep's zero section)
    hipMemsetAsync(deg, 0, (NND + 1) * sizeof(int), stream);

    // fused prep (bounds | x->fp16 | W->fp16^T | count atomics)
    prep_kernel<<<196 + XBLK + 640 + SCATBLK, 256, 0, stream>>>(
        batch, deg, gstart, (const float4*)x, (half4*)act16,
        W[0], W[1], W[2], wt0, wt1, wt2, ei);
    scan_part_kernel<<<NBLK, 256, 0, stream>>>(deg, bsum);
    scan_write_kernel<<<NBLK, 256, 0, stream>>>(deg, bsum, rowptr, cursor);

    // 3 GAT layers; layer 0's gemm carries the CSR scatter as extra blocks
    int K = FEAT;
    for (int l = 0; l < 3; l++) {
        int grid = (l == 0) ? (GEMMBLK + SCATBLK) : GEMMBLK;
        gemm_mfma_kernel<<<grid, 256, 0, stream>>>(act16, wt[l], As[l], Ad[l], H16,
                                                   asrc, adst, K, GEMMBLK,
                                                   ei, cursor, csrsrc);
        agg_kernel<<<(NND + 3) / 4, 256, 0, stream>>>(H16, asrc, adst, rowptr, csrsrc,
                                                      (const float4*)Bb[l], (half8*)act16);
        K = CCH;
    }

    // global mean pool + final linear + L2 normalize (fused)
    poolfinal_kernel<<<NG, 1024, 0, stream>>>(act16, gstart, Wf, bf, out);
}